// Round 1
// 630.635 us; speedup vs baseline: 1.0200x; 1.0200x over previous
//
#include <hip/hip_runtime.h>

#define H 1024
#define NB 5
#define TSTRIDE 131072  // T*H = 128*1024, row stride of features; enc[b,k] = features[b*TSTRIDE + k]

#define BM 64
#define BN 64
#define BK 32

__device__ __forceinline__ float sign_val(float h, float g, float pre, float a) {
    float cand = (pre >= 0.0f) ? pre : a * pre;
    float v = h + g * cand;
    // v==0 -> 0.1 -> sign +1, so v>=0 maps to +1; NaN maps to -1 (same as before)
    return (v >= 0.0f) ? 1.0f : -1.0f;
}

// One block per output column j: gate[n][j] = sigmoid(enc[j]·(h[n]+keys[n])),
// base[n][j] = h[n]·Uw[j] + keys[n]·Vw[j].  256 threads x float4 = 1024 k in one pass.
__global__ __launch_bounds__(256) void prep_kernel(
    const float* __restrict__ features,
    const float* __restrict__ states,
    const float* __restrict__ Uw,
    const float* __restrict__ Vw,
    const float* __restrict__ keys,
    float* __restrict__ gateT,   // [NB][H]
    float* __restrict__ baseT)   // [NB][H]
{
    const int j = blockIdx.x;
    const int tid = (int)threadIdx.x;
    const int k4 = tid << 2;

    const float4 e = *(const float4*)(features + (size_t)j * TSTRIDE + k4);
    const float4 u = *(const float4*)(Uw + (size_t)j * H + k4);
    const float4 v = *(const float4*)(Vw + (size_t)j * H + k4);

    float accg[NB], accb[NB];
    #pragma unroll
    for (int n = 0; n < NB; ++n) {
        const float4 hk = *(const float4*)(states + n * H + k4);
        const float4 ky = *(const float4*)(keys + n * H + k4);
        accg[n] = e.x * (hk.x + ky.x) + e.y * (hk.y + ky.y)
                + e.z * (hk.z + ky.z) + e.w * (hk.w + ky.w);
        accb[n] = hk.x * u.x + hk.y * u.y + hk.z * u.z + hk.w * u.w
                + ky.x * v.x + ky.y * v.y + ky.z * v.z + ky.w * v.w;
    }

    __shared__ float red[2 * NB][4];
    #pragma unroll
    for (int n = 0; n < NB; ++n) {
        float g = accg[n], b = accb[n];
        #pragma unroll
        for (int off = 32; off > 0; off >>= 1) {
            g += __shfl_down(g, (unsigned)off, 64);
            b += __shfl_down(b, (unsigned)off, 64);
        }
        if ((tid & 63) == 0) {
            red[n][tid >> 6] = g;
            red[NB + n][tid >> 6] = b;
        }
    }
    __syncthreads();
    if (tid < 2 * NB) {
        const float s = red[tid][0] + red[tid][1] + red[tid][2] + red[tid][3];
        if (tid < NB) {
            gateT[tid * H + j] = 1.0f / (1.0f + expf(-s));
        } else {
            baseT[(tid - NB) * H + j] = s;
        }
    }
}

// Swizzled LDS store: element (k, row) lives at [k][ (g ^ (k>>2))*4 + r ],
// g=row>>2, r=row&3.  kq is a multiple of 4 so (kq+i)>>2 is constant -> one col.
// Write banks: (4*(g^q)+r) mod 32 with q=kq>>2 covers all 32 banks 2-way (free).
// Reads stay 16B-aligned ds_read_b128 at col-group (ty ^ (kk>>2)).
__device__ __forceinline__ void stash_tile(float (*dst)[64], int row, int kq, float4 v) {
    const int g = row >> 2, r = row & 3;
    const int col = ((g ^ (kq >> 2)) << 2) | r;
    dst[kq + 0][col] = v.x;
    dst[kq + 1][col] = v.y;
    dst[kq + 2][col] = v.z;
    dst[kq + 3][col] = v.w;
}

// Tiled f32 GEMM E[b,j] = enc[b,:]·Ww[j,:] with fused sign epilogue.
// Double-buffered LDS + register prefetch: one barrier per k-tile,
// global latency hidden under the 32-step FMA loop.
__global__ __launch_bounds__(256) void gemm_sign_kernel(
    const float* __restrict__ features,
    const float* __restrict__ Ww,
    const float* __restrict__ states,
    const float* __restrict__ prelu_a,
    const float* __restrict__ gateT,
    const float* __restrict__ baseT,
    float* __restrict__ out)
{
    __shared__ float As[2][BK][64];  // As[buf][k][swizzled row]
    __shared__ float Bs[2][BK][64];
    const int bb = blockIdx.y * BM;
    const int jb = blockIdx.x * BN;
    const int tid = (int)threadIdx.x;
    const int tx = tid & 15;   // j group
    const int ty = tid >> 4;   // b group

    // staging geometry: thread covers rows {row0, row0+32} x 4 k's
    const int row0 = tid >> 3;           // 0..31
    const int kq   = (tid & 7) << 2;     // 0,4,..,28
    const float* aptr0 = features + (size_t)(bb + row0) * TSTRIDE + kq;
    const float* aptr1 = features + (size_t)(bb + row0 + 32) * TSTRIDE + kq;
    const float* bptr0 = Ww + (size_t)(jb + row0) * H + kq;
    const float* bptr1 = Ww + (size_t)(jb + row0 + 32) * H + kq;

    float acc[4][4] = {};

    // prologue: stage tile 0 into buffer 0
    {
        const float4 a0 = *(const float4*)(aptr0);
        const float4 a1 = *(const float4*)(aptr1);
        const float4 b0 = *(const float4*)(bptr0);
        const float4 b1 = *(const float4*)(bptr1);
        stash_tile(As[0], row0,      kq, a0);
        stash_tile(As[0], row0 + 32, kq, a1);
        stash_tile(Bs[0], row0,      kq, b0);
        stash_tile(Bs[0], row0 + 32, kq, b1);
    }
    __syncthreads();

    const int NT = H / BK;
    for (int t = 0; t < NT; ++t) {
        const int cur = t & 1;
        float4 a0, a1, b0, b1;
        const bool pf = (t + 1 < NT);
        if (pf) {
            const int off = (t + 1) * BK;
            a0 = *(const float4*)(aptr0 + off);
            a1 = *(const float4*)(aptr1 + off);
            b0 = *(const float4*)(bptr0 + off);
            b1 = *(const float4*)(bptr1 + off);
        }
        #pragma unroll
        for (int kk = 0; kk < BK; ++kk) {
            const int sw = kk >> 2;
            const float4 a = *(const float4*)&As[cur][kk][(ty ^ sw) << 2];
            const float4 b = *(const float4*)&Bs[cur][kk][(tx ^ sw) << 2];
            acc[0][0] += a.x * b.x; acc[0][1] += a.x * b.y; acc[0][2] += a.x * b.z; acc[0][3] += a.x * b.w;
            acc[1][0] += a.y * b.x; acc[1][1] += a.y * b.y; acc[1][2] += a.y * b.z; acc[1][3] += a.y * b.w;
            acc[2][0] += a.z * b.x; acc[2][1] += a.z * b.y; acc[2][2] += a.z * b.z; acc[2][3] += a.z * b.w;
            acc[3][0] += a.w * b.x; acc[3][1] += a.w * b.y; acc[3][2] += a.w * b.z; acc[3][3] += a.w * b.w;
        }
        if (pf) {
            const int nxt = cur ^ 1;
            stash_tile(As[nxt], row0,      kq, a0);
            stash_tile(As[nxt], row0 + 32, kq, a1);
            stash_tile(Bs[nxt], row0,      kq, b0);
            stash_tile(Bs[nxt], row0 + 32, kq, b1);
        }
        __syncthreads();
    }

    // Epilogue: out[(n*1024 + b)*1024 + j] = sign(h[n,j] + gate[j,n]*prelu(base[n,j]+E[b,j]))
    const int c = jb + (tx << 2);
    const float4 pa = *(const float4*)(prelu_a + c);
    #pragma unroll
    for (int n = 0; n < NB; ++n) {
        const float4 hv = *(const float4*)(states + n * H + c);
        const float4 gv = *(const float4*)(gateT + n * H + c);
        const float4 sv = *(const float4*)(baseT + n * H + c);
        #pragma unroll
        for (int i = 0; i < 4; ++i) {
            float4 o;
            o.x = sign_val(hv.x, gv.x, sv.x + acc[i][0], pa.x);
            o.y = sign_val(hv.y, gv.y, sv.y + acc[i][1], pa.y);
            o.z = sign_val(hv.z, gv.z, sv.z + acc[i][2], pa.z);
            o.w = sign_val(hv.w, gv.w, sv.w + acc[i][3], pa.w);
            const int row = bb + (ty << 2) + i;
            *(float4*)(out + ((size_t)(n * H + row) * H + c)) = o;
        }
    }
}

extern "C" void kernel_launch(void* const* d_in, const int* in_sizes, int n_in,
                              void* d_out, int out_size, void* d_ws, size_t ws_size,
                              hipStream_t stream) {
    const float* features = (const float*)d_in[0];
    const float* states   = (const float*)d_in[1];
    const float* Uw       = (const float*)d_in[2];
    const float* Vw       = (const float*)d_in[3];
    const float* Ww       = (const float*)d_in[4];
    const float* keys     = (const float*)d_in[5];
    const float* prelu_a  = (const float*)d_in[6];
    float* out = (float*)d_out;

    float* gateT = (float*)d_ws;          // NB*H floats
    float* baseT = gateT + NB * H;        // NB*H floats

    prep_kernel<<<H, 256, 0, stream>>>(features, states, Uw, Vw, keys, gateT, baseT);

    dim3 grid(H / BN, H / BM);
    gemm_sign_kernel<<<grid, 256, 0, stream>>>(features, Ww, states, prelu_a,
                                               gateT, baseT, out);
}

// Round 2
// 628.227 us; speedup vs baseline: 1.0239x; 1.0038x over previous
//
#include <hip/hip_runtime.h>

#define H 1024
#define NB 5
#define TSTRIDE 131072  // T*H = 128*1024, row stride of features; enc[b,k] = features[b*TSTRIDE + k]

#define BM 32
#define BN 64
#define BK 32

__device__ __forceinline__ float sign_val(float h, float g, float pre, float a) {
    float cand = (pre >= 0.0f) ? pre : a * pre;
    float v = h + g * cand;
    // v==0 -> 0.1 -> sign +1, so v>=0 maps to +1; NaN maps to -1 (same as before)
    return (v >= 0.0f) ? 1.0f : -1.0f;
}

// One block per output column j: gate[n][j] = sigmoid(enc[j]·(h[n]+keys[n])),
// base[n][j] = h[n]·Uw[j] + keys[n]·Vw[j].  256 threads x float4 = 1024 k in one pass.
__global__ __launch_bounds__(256) void prep_kernel(
    const float* __restrict__ features,
    const float* __restrict__ states,
    const float* __restrict__ Uw,
    const float* __restrict__ Vw,
    const float* __restrict__ keys,
    float* __restrict__ gateT,   // [NB][H]
    float* __restrict__ baseT)   // [NB][H]
{
    const int j = blockIdx.x;
    const int tid = (int)threadIdx.x;
    const int k4 = tid << 2;

    const float4 e = *(const float4*)(features + (size_t)j * TSTRIDE + k4);
    const float4 u = *(const float4*)(Uw + (size_t)j * H + k4);
    const float4 v = *(const float4*)(Vw + (size_t)j * H + k4);

    float accg[NB], accb[NB];
    #pragma unroll
    for (int n = 0; n < NB; ++n) {
        const float4 hk = *(const float4*)(states + n * H + k4);
        const float4 ky = *(const float4*)(keys + n * H + k4);
        accg[n] = e.x * (hk.x + ky.x) + e.y * (hk.y + ky.y)
                + e.z * (hk.z + ky.z) + e.w * (hk.w + ky.w);
        accb[n] = hk.x * u.x + hk.y * u.y + hk.z * u.z + hk.w * u.w
                + ky.x * v.x + ky.y * v.y + ky.z * v.z + ky.w * v.w;
    }

    __shared__ float red[2 * NB][4];
    #pragma unroll
    for (int n = 0; n < NB; ++n) {
        float g = accg[n], b = accb[n];
        #pragma unroll
        for (int off = 32; off > 0; off >>= 1) {
            g += __shfl_down(g, (unsigned)off, 64);
            b += __shfl_down(b, (unsigned)off, 64);
        }
        if ((tid & 63) == 0) {
            red[n][tid >> 6] = g;
            red[NB + n][tid >> 6] = b;
        }
    }
    __syncthreads();
    if (tid < 2 * NB) {
        const float s = red[tid][0] + red[tid][1] + red[tid][2] + red[tid][3];
        if (tid < NB) {
            gateT[tid * H + j] = 1.0f / (1.0f + expf(-s));
        } else {
            baseT[(tid - NB) * H + j] = s;
        }
    }
}

// Swizzled LDS store: element (k, row) lives at [k][ ((g ^ (k>>2))<<2) | r ],
// g=row>>2, r=row&3.  kq is a multiple of 4 so (kq+i)>>2 is constant -> one col.
// Per-wave: row-group g spans only 2 values per staging instruction -> writes are
// 2-way bank aliased (free, m136).  Reads stay aligned at col-group (idx ^ (kk>>2)).
template <int NROW>
__device__ __forceinline__ void stash(float (*dst)[NROW], int row, int kq, float4 v) {
    const int g = row >> 2, r = row & 3;
    const int col = ((g ^ (kq >> 2)) << 2) | r;
    dst[kq + 0][col] = v.x;
    dst[kq + 1][col] = v.y;
    dst[kq + 2][col] = v.z;
    dst[kq + 3][col] = v.w;
}

// Tiled f32 GEMM E[b,j] = enc[b,:]·Ww[j,:] with fused sign epilogue.
// BM=32 x BN=64 -> grid 512 = 2 blocks/CU (2 waves/SIMD): independent blocks
// cover each other's barrier drain.  Double-buffered LDS + register prefetch.
__global__ __launch_bounds__(256) void gemm_sign_kernel(
    const float* __restrict__ features,
    const float* __restrict__ Ww,
    const float* __restrict__ states,
    const float* __restrict__ prelu_a,
    const float* __restrict__ gateT,
    const float* __restrict__ baseT,
    float* __restrict__ out)
{
    __shared__ float As[2][BK][BM];  // As[buf][k][swizzled row], 8 KB
    __shared__ float Bs[2][BK][BN];  // 16 KB
    const int bb = blockIdx.y * BM;
    const int jb = blockIdx.x * BN;
    const int tid = (int)threadIdx.x;
    const int tx = tid & 15;   // j group: 4 cols each
    const int ty = tid >> 4;   // b group: 2 rows each

    // staging geometry: A is one float4/thread (32x32), B is two (64x32)
    const int row0 = tid >> 3;           // 0..31
    const int kq   = (tid & 7) << 2;     // 0,4,..,28
    const float* aptr  = features + (size_t)(bb + row0) * TSTRIDE + kq;
    const float* bptr0 = Ww + (size_t)(jb + row0) * H + kq;
    const float* bptr1 = Ww + (size_t)(jb + row0 + 32) * H + kq;

    float acc[2][4] = {};

    // prologue: stage tile 0 into buffer 0
    {
        const float4 a0 = *(const float4*)(aptr);
        const float4 b0 = *(const float4*)(bptr0);
        const float4 b1 = *(const float4*)(bptr1);
        stash<BM>(As[0], row0,      kq, a0);
        stash<BN>(Bs[0], row0,      kq, b0);
        stash<BN>(Bs[0], row0 + 32, kq, b1);
    }
    __syncthreads();

    const int gA = ty >> 1;            // A row-group of this thread
    const int rA = (ty & 1) << 1;      // row-within-group offset (2 rows, contiguous)

    const int NT = H / BK;
    for (int t = 0; t < NT; ++t) {
        const int cur = t & 1;
        float4 a0, b0, b1;
        const bool pf = (t + 1 < NT);
        if (pf) {
            const int off = (t + 1) * BK;
            a0 = *(const float4*)(aptr + off);
            b0 = *(const float4*)(bptr0 + off);
            b1 = *(const float4*)(bptr1 + off);
        }
        #pragma unroll
        for (int kk = 0; kk < BK; ++kk) {
            const int sw = kk >> 2;
            const float2 a = *(const float2*)&As[cur][kk][((gA ^ sw) << 2) | rA];
            const float4 b = *(const float4*)&Bs[cur][kk][(tx ^ sw) << 2];
            acc[0][0] += a.x * b.x; acc[0][1] += a.x * b.y; acc[0][2] += a.x * b.z; acc[0][3] += a.x * b.w;
            acc[1][0] += a.y * b.x; acc[1][1] += a.y * b.y; acc[1][2] += a.y * b.z; acc[1][3] += a.y * b.w;
        }
        if (pf) {
            const int nxt = cur ^ 1;
            stash<BM>(As[nxt], row0,      kq, a0);
            stash<BN>(Bs[nxt], row0,      kq, b0);
            stash<BN>(Bs[nxt], row0 + 32, kq, b1);
        }
        __syncthreads();
    }

    // Epilogue: out[(n*1024 + b)*1024 + j] = sign(h[n,j] + gate[j,n]*prelu(base[n,j]+E[b,j]))
    const int c = jb + (tx << 2);
    const float4 pa = *(const float4*)(prelu_a + c);
    #pragma unroll
    for (int n = 0; n < NB; ++n) {
        const float4 hv = *(const float4*)(states + n * H + c);
        const float4 gv = *(const float4*)(gateT + n * H + c);
        const float4 sv = *(const float4*)(baseT + n * H + c);
        #pragma unroll
        for (int i = 0; i < 2; ++i) {
            float4 o;
            o.x = sign_val(hv.x, gv.x, sv.x + acc[i][0], pa.x);
            o.y = sign_val(hv.y, gv.y, sv.y + acc[i][1], pa.y);
            o.z = sign_val(hv.z, gv.z, sv.z + acc[i][2], pa.z);
            o.w = sign_val(hv.w, gv.w, sv.w + acc[i][3], pa.w);
            const int row = bb + (ty << 1) + i;
            *(float4*)(out + ((size_t)(n * H + row) * H + c)) = o;
        }
    }
}

extern "C" void kernel_launch(void* const* d_in, const int* in_sizes, int n_in,
                              void* d_out, int out_size, void* d_ws, size_t ws_size,
                              hipStream_t stream) {
    const float* features = (const float*)d_in[0];
    const float* states   = (const float*)d_in[1];
    const float* Uw       = (const float*)d_in[2];
    const float* Vw       = (const float*)d_in[3];
    const float* Ww       = (const float*)d_in[4];
    const float* keys     = (const float*)d_in[5];
    const float* prelu_a  = (const float*)d_in[6];
    float* out = (float*)d_out;

    float* gateT = (float*)d_ws;          // NB*H floats
    float* baseT = gateT + NB * H;        // NB*H floats

    prep_kernel<<<H, 256, 0, stream>>>(features, states, Uw, Vw, keys, gateT, baseT);

    dim3 grid(H / BN, H / BM);
    gemm_sign_kernel<<<grid, 256, 0, stream>>>(features, Ww, states, prelu_a,
                                               gateT, baseT, out);
}